// Round 1
// baseline (342.992 us; speedup 1.0000x reference)
//
#include <hip/hip_runtime.h>
#include <hip/hip_bf16.h>

// GAT on two 512-node cliques + bipartite cross edges, 5 GATConv layers.
//
// R14 = R13 (168.7us, absmax 0) with the 6 hot kernels fused into ONE
// persistent kernel (grid 256x512, co-resident by construction: 1 block/CU,
// 256 blocks == 256 CUs) using a device-scope software grid barrier between
// phases.  Counters showed no pipe saturated (HBM 1.5%, VALU 7.6%, occ 5%)
// -> the floor was 7 serial kernel dispatches, each paying launch/ramp
// latency.  prep stays separate: it zero-inits the barrier words (workspace
// is poisoned by the harness) and completes via stream order before the
// fused kernel starts.  All phase bodies are verbatim R13 (same accumulation
// order -> bit-identical output).  Per-phase __shared__ overlaps in one raw
// 18.9KB buffer.

typedef __hip_bfloat16 bf16;

__device__ __forceinline__ float b2f(bf16 x) { return __bfloat162float(x); }

__device__ __forceinline__ int detect_bf16(const void* desc1) {
  const unsigned* u = (const unsigned*)desc1;
  int hits = 0;
#pragma unroll 8
  for (int i = 0; i < 256; ++i) {
    unsigned e = (u[i] >> 7) & 0xFFu;
    hits += (e >= 100u && e <= 140u) ? 1 : 0;
  }
  return hits >= 200 ? 1 : 0;
}

__device__ __forceinline__ float load_in(const void* p, int i, int bf) {
  return bf ? b2f(((const bf16*)p)[i]) : ((const float*)p)[i];
}

// ---------------------------------------------------------------- prep ----
// xt written in packed layout: xt[((c>>2)*1024 + n)*4 + (c&3)].
// Also zeroes the grid-barrier words (workspace arrives poisoned).
__global__ __launch_bounds__(256) void prep_kernel(
    const void* __restrict__ desc1, const void* __restrict__ desc2,
    const void* __restrict__ W1,   const void* __restrict__ as1,
    const void* __restrict__ ad1,  const void* __restrict__ b1,
    const void* __restrict__ W2,   const void* __restrict__ as2,
    const void* __restrict__ ad2,  const void* __restrict__ b2,
    float* __restrict__ xt, float* __restrict__ W1f, float* __restrict__ W2f,
    float* __restrict__ vecs, int* __restrict__ flag,
    unsigned* __restrict__ bar) {
  const int bf = detect_bf16(desc1);
  if (blockIdx.x == 0 && threadIdx.x == 0) {
    *flag = bf;
    bar[0] = 0u;  // arrive counter
    bar[1] = 0u;  // generation
  }
  const int total = 131072 + 16384 + 16384 + 6 * 128;
  for (int idx = blockIdx.x * blockDim.x + threadIdx.x; idx < total;
       idx += gridDim.x * blockDim.x) {
    if (idx < 131072) {
      int n = idx & 1023, c = idx >> 10;
      float v = (n < 512) ? load_in(desc1, n * 128 + c, bf)
                          : load_in(desc2, (n - 512) * 128 + c, bf);
      xt[((c >> 2) * 1024 + n) * 4 + (c & 3)] = v;
    } else if (idx < 147456) {
      W1f[idx - 131072] = load_in(W1, idx - 131072, bf);
    } else if (idx < 163840) {
      W2f[idx - 147456] = load_in(W2, idx - 147456, bf);
    } else {
      int i = idx - 163840, o = i & 127;
      float v;
      if      (i < 128) v = load_in(as1, o, bf);
      else if (i < 256) v = load_in(ad1, o, bf);
      else if (i < 384) v = load_in(b1, o, bf);
      else if (i < 512) v = load_in(as2, o, bf);
      else if (i < 640) v = load_in(ad2, o, bf);
      else              v = load_in(b2, o, bf);
      vecs[i] = v;
    }
  }
}

// ------------------------------------------------------ grid barrier ----
// Device-scope sense-free barrier: monotone generation counter.  All 256
// blocks are co-resident (grid == CU count, 1 block/CU guaranteed by
// launch bounds), so spinning is deadlock-free.
__device__ __forceinline__ void grid_sync(unsigned* bar) {
  __syncthreads();
  if (threadIdx.x == 0) {
    __threadfence();  // make this block's writes agent-visible
    unsigned g = __hip_atomic_load(&bar[1], __ATOMIC_RELAXED,
                                   __HIP_MEMORY_SCOPE_AGENT);
    unsigned a = __hip_atomic_fetch_add(&bar[0], 1u, __ATOMIC_ACQ_REL,
                                        __HIP_MEMORY_SCOPE_AGENT);
    if (a == gridDim.x - 1) {
      __hip_atomic_store(&bar[0], 0u, __ATOMIC_RELAXED,
                         __HIP_MEMORY_SCOPE_AGENT);
      __hip_atomic_fetch_add(&bar[1], 1u, __ATOMIC_RELEASE,
                             __HIP_MEMORY_SCOPE_AGENT);
    } else {
      while (__hip_atomic_load(&bar[1], __ATOMIC_ACQUIRE,
                               __HIP_MEMORY_SCOPE_AGENT) == g)
        __builtin_amdgcn_s_sleep(1);
    }
    __threadfence();  // order subsequent reads after the acquire
  }
  __syncthreads();
}

// ------------------------------------------------------- GAT layer phase ----
// block = (S<<7)|hd, 512 threads.  Sources = set S; dst = S (inside) or
// 1-S (cross).  Thread tid owns src node S*512+tid AND dst node D*512+tid.
// Body verbatim from R13's layer_kernel; __shared__ carved from smem.
template <int CROSS>
__device__ __forceinline__ void layer_phase(
    char* smem, const float* __restrict__ xt_in, float* __restrict__ xt_out,
    const float* __restrict__ Wf, const float* __restrict__ vecs) {
  float*    sS      = (float*)(smem);            // 512 f   bucket-ordered s
  float*    sH      = (float*)(smem + 2048);     // 512 f   bucket-ordered h
  unsigned* hA      = (unsigned*)(smem + 4096);  // 512 u   histogram
  unsigned* ISb     = (unsigned*)(smem + 6144);  // 512 u   inclusive scan
  unsigned* binNext = (unsigned*)(smem + 8192);  // 512 u
  float2*   PRE     = (float2*)(smem + 10240);   // 512 f2  incl. prefix
  float2*   SUF     = (float2*)(smem + 14336);   // 512 f2  incl. suffix
  float*    red     = (float*)(smem + 18432);    // 16 f
  unsigned* wTot    = (unsigned*)(smem + 18496); // 8 u
  float2*   preTot  = (float2*)(smem + 18528);   // 8 f2
  float2*   sufTot  = (float2*)(smem + 18592);   // 8 f2

  const int tid  = threadIdx.x;
  const int lane = tid & 63;
  const int wave = tid >> 6;
  const int hd   = blockIdx.x & 127;
  const int S    = blockIdx.x >> 7;
  const int D    = CROSS ? (1 - S) : S;
  const float a_src = vecs[hd], a_dst = vecs[128 + hd], bias = vecs[256 + hd];

  // Phase A: h column for this head.  Packed layout: 32 float4 loads/thread.
  float accS0 = 0.f, accS1 = 0.f, accD0 = 0.f, accD1 = 0.f;
  {
    const float4* x4 = (const float4*)xt_in;
    const int nS = S * 512 + tid;
    const int nD = D * 512 + tid;
    for (int cc = 0; cc < 32; cc += 8) {
      float4 xs[8], xd[8];
#pragma unroll
      for (int u = 0; u < 8; ++u) {
        xs[u] = x4[(cc + u) * 1024 + nS];
        if (CROSS) xd[u] = x4[(cc + u) * 1024 + nD];
      }
#pragma unroll
      for (int u = 0; u < 8; ++u) {
        const int k = (cc + u) * 4;
        const float w0 = Wf[k * 128 + hd];
        const float w1 = Wf[(k + 1) * 128 + hd];
        const float w2 = Wf[(k + 2) * 128 + hd];
        const float w3 = Wf[(k + 3) * 128 + hd];
        accS0 = fmaf(xs[u].x, w0, accS0);
        accS1 = fmaf(xs[u].y, w1, accS1);
        accS0 = fmaf(xs[u].z, w2, accS0);
        accS1 = fmaf(xs[u].w, w3, accS1);
        if (CROSS) {
          accD0 = fmaf(xd[u].x, w0, accD0);
          accD1 = fmaf(xd[u].y, w1, accD1);
          accD0 = fmaf(xd[u].z, w2, accD0);
          accD1 = fmaf(xd[u].w, w3, accD1);
        }
      }
    }
  }
  const float h_src = accS0 + accS1;
  const float h_dst = CROSS ? (accD0 + accD1) : h_src;
  const float s_own = h_src * a_src;
  const float d_own = h_dst * a_dst;

  // B1: block min/max of s (wave shuffle + LDS combine); zero hist.
  {
    float mnw = s_own, mxw = s_own;
#pragma unroll
    for (int off = 32; off > 0; off >>= 1) {
      mnw = fminf(mnw, __shfl_down(mnw, off));
      mxw = fmaxf(mxw, __shfl_down(mxw, off));
    }
    if (lane == 0) { red[wave] = mnw; red[8 + wave] = mxw; }
  }
  hA[tid] = 0;
  binNext[tid] = 0;
  __syncthreads();                                        // (1)
  const float mn = fminf(fminf(fminf(red[0], red[1]), fminf(red[2], red[3])),
                         fminf(fminf(red[4], red[5]), fminf(red[6], red[7])));
  const float mx = fmaxf(fmaxf(fmaxf(red[8], red[9]), fmaxf(red[10], red[11])),
                         fmaxf(fmaxf(red[12], red[13]), fmaxf(red[14], red[15])));
  const float scale = 512.0f / fmaxf(mx - mn, 1e-20f);

  // B2: histogram (bin(x) monotone non-decreasing).
  const int myBin = (int)fminf(fmaxf((s_own - mn) * scale, 0.0f), 511.0f);
  atomicAdd(&hA[myBin], 1u);
  __syncthreads();                                        // (2)

  // B3: inclusive scan of hist via wave shuffles + wave-total exchange.
  {
    unsigned v = hA[tid];
#pragma unroll
    for (int off = 1; off < 64; off <<= 1) {
      unsigned u = __shfl_up(v, off);
      if (lane >= off) v += u;
    }
    if (lane == 63) wTot[wave] = v;
    __syncthreads();                                      // (3)
    unsigned pre = 0;
#pragma unroll
    for (int w = 0; w < 8; ++w) pre += (w < wave) ? wTot[w] : 0u;
    ISb[tid] = v + pre;
    __syncthreads();                                      // (4)
  }

  // B4: scatter into bucket-ordered arrays (order within bucket free).
  {
    unsigned base = myBin ? ISb[myBin - 1] : 0u;
    unsigned pos = base + atomicAdd(&binNext[myBin], 1u);
    sS[pos] = s_own;
    sH[pos] = h_src;
  }
  __syncthreads();                                        // (5)

  // B5: exps + prefix(e2,e2h) / suffix(e1,e1h) via wave shuffles.
  {
    const float sv = sS[tid];
    const float hv = sH[tid];
    const float e1 = __expf(sv), e2 = __expf(0.2f * sv);
    float p0 = e2, p1 = e2 * hv;     // prefix pair
    float q0 = e1, q1 = e1 * hv;     // suffix pair
#pragma unroll
    for (int off = 1; off < 64; off <<= 1) {
      float u0 = __shfl_up(p0, off), u1 = __shfl_up(p1, off);
      if (lane >= off) { p0 += u0; p1 += u1; }
      float v0 = __shfl_down(q0, off), v1 = __shfl_down(q1, off);
      if (lane + off < 64) { q0 += v0; q1 += v1; }
    }
    if (lane == 63) preTot[wave] = make_float2(p0, p1);
    if (lane == 0)  sufTot[wave] = make_float2(q0, q1);
    __syncthreads();                                      // (6)
    float a0 = 0.f, a1 = 0.f, b0 = 0.f, b1 = 0.f;
#pragma unroll
    for (int w = 0; w < 8; ++w) {
      float2 pt = preTot[w], st = sufTot[w];
      if (w < wave) { a0 += pt.x; a1 += pt.y; }
      if (w > wave) { b0 += st.x; b1 += st.y; }
    }
    PRE[tid] = make_float2(p0 + a0, p1 + a1);
    SUF[tid] = make_float2(q0 + b0, q1 + b1);
    __syncthreads();                                      // (7)
  }

  // B7: per destination: bucket lookup + boundary-exact combine.
  {
    const float theta = -d_own;
    int b = (int)fminf(fmaxf((theta - mn) * scale, 0.0f), 511.0f);
    unsigned k0 = b ? ISb[b - 1] : 0u;  // elems in buckets < b: s < theta
    unsigned k1 = ISb[b];               // elems in buckets <= b
    float F1 = __expf(d_own), F2 = __expf(0.2f * d_own);
    float P2 = 0.f, P2h = 0.f, S1 = 0.f, S1h = 0.f;
    if (k0 > 0)   { float2 t2 = PRE[k0 - 1]; P2 = t2.x; P2h = t2.y; }
    if (k1 < 512) { float2 t2 = SUF[k1];     S1 = t2.x; S1h = t2.y; }
    float den = F1 * S1 + F2 * P2;
    float num = F1 * S1h + F2 * P2h;
    for (unsigned e = k0; e < k1; ++e) {  // boundary bucket: exact compare
      float se = sS[e], he = sH[e];
      float p = (se >= theta) ? F1 * __expf(se) : F2 * __expf(0.2f * se);
      den += p;
      num = fmaf(p, he, num);
    }
    if (CROSS) {  // self-loop: dst node's own source score
      float t = h_dst * a_src + d_own;
      float p = __expf(fmaxf(t, 0.2f * t));
      den += p;
      num = fmaf(p, h_dst, num);
    }
    float o = num / (den + 1e-16f) + bias;
    o = (o > 0.f) ? o : expm1f(o);  // ELU
    // packed layout: xt_out[((hd>>2)*1024 + node)*4 + (hd&3)]
    xt_out[(((hd >> 2) * 1024) + D * 512 + tid) * 4 + (hd & 3)] = o;
  }
}

// ----------------------------------------------------- final layer: mm2 ----
// 256 blocks x 512 threads: 4 rows x 128 cols per block (was 2x128 at 256
// threads).  Same per-output arithmetic and accumulation order as R13.
__device__ __forceinline__ void mm2_phase(
    char* smem, const float* __restrict__ xt_in, const float* __restrict__ W2f,
    const float* __restrict__ vecs, float* __restrict__ h2,
    float* __restrict__ s2, float* __restrict__ d2) {
  float* rs = (float*)(smem);
  float* rd = (float*)(smem + 2048);
  const int tid = threadIdx.x;
  const int row = blockIdx.x * 4 + (tid >> 7);
  const int c = tid & 127;
  float acc0 = 0.f, acc1 = 0.f;
  {
    const float4* x4 = (const float4*)xt_in;
    for (int cc = 0; cc < 32; cc += 8) {
      float4 xb[8];
#pragma unroll
      for (int u = 0; u < 8; ++u) xb[u] = x4[(cc + u) * 1024 + row];
#pragma unroll
      for (int u = 0; u < 8; ++u) {
        const int k = (cc + u) * 4;
        acc0 = fmaf(xb[u].x, W2f[k * 128 + c],       acc0);
        acc1 = fmaf(xb[u].y, W2f[(k + 1) * 128 + c], acc1);
        acc0 = fmaf(xb[u].z, W2f[(k + 2) * 128 + c], acc0);
        acc1 = fmaf(xb[u].w, W2f[(k + 3) * 128 + c], acc1);
      }
    }
  }
  float acc = acc0 + acc1;
  h2[row * 128 + c] = acc;
  rs[tid] = acc * vecs[384 + c];  // a_src2
  rd[tid] = acc * vecs[512 + c];  // a_dst2
  __syncthreads();
  for (int off = 64; off > 0; off >>= 1) {
    if ((tid & 127) < off) { rs[tid] += rs[tid + off]; rd[tid] += rd[tid + off]; }
    __syncthreads();
  }
  if ((tid & 127) == 0) {
    s2[row] = rs[tid];
    d2[row] = rd[tid];
  }
}

// ---------------------------------------------------- final layer: attn ----
// 256 blocks x 512 threads: 4 dsts/block, one dst per 128-thread group
// (was 2 per group at 256 threads).  Same per-output arithmetic as R13.
__device__ __forceinline__ void att2_phase(
    char* smem, const float* __restrict__ h2, const float* __restrict__ s2,
    const float* __restrict__ d2, const float* __restrict__ vecs,
    void* __restrict__ out, int bf) {
  float* pT = (float*)smem;  // pT[j*4 + ld], 2048 floats
  const int tid = threadIdx.x;
  const int dstBase = blockIdx.x * 4;
  const int srcBase = (dstBase < 512) ? 512 : 0;  // cross edges

  for (int e = tid; e < 2048; e += 512) {
    int j = e >> 2, ld = e & 3;
    float t = s2[srcBase + j] + d2[dstBase + ld];
    pT[e] = __expf(fmaxf(t, 0.2f * t));
  }
  __syncthreads();

  const int c = tid & 127;
  const int g = tid >> 7;            // 0..3 -> dst within block
  const int i0 = dstBase + g;
  float den = 0.f, num = 0.f;
  const float* hrow = h2 + srcBase * 128 + c;
  for (int j0 = 0; j0 < 512; j0 += 8) {
    float hb[8];
#pragma unroll
    for (int u = 0; u < 8; ++u) hb[u] = hrow[(j0 + u) * 128];
#pragma unroll
    for (int u = 0; u < 8; ++u) {
      float p = pT[(j0 + u) * 4 + g];
      den += p;
      num = fmaf(p, hb[u], num);
    }
  }
  // self-loop
  float ts = s2[i0] + d2[i0];
  float ps = __expf(fmaxf(ts, 0.2f * ts));
  den += ps;
  num = fmaf(ps, h2[i0 * 128 + c], num);

  float o = num / (den + 1e-16f) + vecs[640 + c];
  if (bf) ((bf16*)out)[i0 * 128 + c] = __float2bfloat16(o);
  else    ((float*)out)[i0 * 128 + c] = o;
}

// ------------------------------------------------------ fused persistent ----
__global__ __launch_bounds__(512, 2) void fused_kernel(
    float* __restrict__ xtA, float* __restrict__ xtB,
    const float* __restrict__ W1f, const float* __restrict__ W2f,
    const float* __restrict__ vecs, float* __restrict__ h2,
    float* __restrict__ s2, float* __restrict__ d2,
    void* __restrict__ out, const int* __restrict__ flag,
    unsigned* __restrict__ bar) {
  __shared__ __align__(16) char smem[18944];

  layer_phase<0>(smem, xtA, xtB, W1f, vecs);  // L1 inside
  grid_sync(bar);
  layer_phase<1>(smem, xtB, xtA, W1f, vecs);  // L2 cross
  grid_sync(bar);
  layer_phase<0>(smem, xtA, xtB, W1f, vecs);  // L3 inside
  grid_sync(bar);
  layer_phase<1>(smem, xtB, xtA, W1f, vecs);  // L4 cross
  grid_sync(bar);
  mm2_phase(smem, xtA, W2f, vecs, h2, s2, d2);
  grid_sync(bar);
  att2_phase(smem, h2, s2, d2, vecs, out, *flag);
}

// ------------------------------------------------------------- launcher ----
extern "C" void kernel_launch(void* const* d_in, const int* in_sizes, int n_in,
                              void* d_out, int out_size, void* d_ws, size_t ws_size,
                              hipStream_t stream) {
  (void)in_sizes; (void)n_in; (void)out_size; (void)ws_size;
  float* ws   = (float*)d_ws;
  float* xtA  = ws;            // 131072 (packed float4 layout)
  float* xtB  = ws + 131072;   // 131072 (packed float4 layout)
  float* h2   = ws + 262144;   // 131072 (row-major)
  float* W1f  = ws + 393216;   // 16384
  float* W2f  = ws + 409600;   // 16384
  float* vecs = ws + 425984;   // 768
  float* s2   = ws + 426752;   // 1024
  float* d2   = ws + 427776;   // 1024
  int*   flag = (int*)(ws + 428800);
  unsigned* bar = (unsigned*)(ws + 428804);  // [arrive, gen]

  prep_kernel<<<64, 256, 0, stream>>>(d_in[0], d_in[1], d_in[2], d_in[3],
                                      d_in[4], d_in[5], d_in[6], d_in[7],
                                      d_in[8], d_in[9], xtA, W1f, W2f, vecs,
                                      flag, bar);
  fused_kernel<<<256, 512, 0, stream>>>(xtA, xtB, W1f, W2f, vecs, h2, s2, d2,
                                        d_out, flag, bar);
}

// Round 2
// 166.203 us; speedup vs baseline: 2.0637x; 2.0637x over previous
//
#include <hip/hip_runtime.h>
#include <hip/hip_bf16.h>

// GAT on two 512-node cliques + bipartite cross edges, 5 GATConv layers.
//
// R15: revert R14's persistent-kernel grid barrier (cross-XCD atomic barrier
// cost ~40us each -> 343us, worse than R13's 168.7us).  Real bottleneck per
// round-0 counters: each layer_kernel is LATENCY-bound (VALUBusy 7.6%, HBM
// 1.5%, 8 waves/CU) on a ~160-deep per-thread global-load chain in phase A.
// Fix: split each layer into
//   gemm_kernel: Ht[hd][node] = (X@W1) column, W column staged in LDS
//                (512 blocks x 256 thr = 2 blocks/CU, coalesced float4 reads)
//   attn_kernel: bucket-softmax per (S,hd); phase A is now TWO coalesced
//                loads from Ht instead of 160 chained loads (and the cross
//                layers no longer compute h twice).
// att2 likewise rebalanced to 512 blocks x 2 dsts (2 blocks/CU).
// All FMA orders and operand values preserved -> bit-identical output.
// Ht aliases h2 (h2 dead until mm2) -> workspace footprint unchanged.

typedef __hip_bfloat16 bf16;

__device__ __forceinline__ float b2f(bf16 x) { return __bfloat162float(x); }

__device__ __forceinline__ int detect_bf16(const void* desc1) {
  const unsigned* u = (const unsigned*)desc1;
  int hits = 0;
#pragma unroll 8
  for (int i = 0; i < 256; ++i) {
    unsigned e = (u[i] >> 7) & 0xFFu;
    hits += (e >= 100u && e <= 140u) ? 1 : 0;
  }
  return hits >= 200 ? 1 : 0;
}

__device__ __forceinline__ float load_in(const void* p, int i, int bf) {
  return bf ? b2f(((const bf16*)p)[i]) : ((const float*)p)[i];
}

// ---------------------------------------------------------------- prep ----
// xt packed: xt[((c>>2)*1024 + n)*4 + (c&3)].
// W1t transposed: W1t[hd*128 + k] = W1[k*128 + hd]  (coalesced LDS staging).
// W2f row-major (mm2 reads it coalesced).
__global__ __launch_bounds__(256) void prep_kernel(
    const void* __restrict__ desc1, const void* __restrict__ desc2,
    const void* __restrict__ W1,   const void* __restrict__ as1,
    const void* __restrict__ ad1,  const void* __restrict__ b1,
    const void* __restrict__ W2,   const void* __restrict__ as2,
    const void* __restrict__ ad2,  const void* __restrict__ b2,
    float* __restrict__ xt, float* __restrict__ W1t, float* __restrict__ W2f,
    float* __restrict__ vecs, int* __restrict__ flag) {
  const int bf = detect_bf16(desc1);
  if (blockIdx.x == 0 && threadIdx.x == 0) *flag = bf;
  const int total = 131072 + 16384 + 16384 + 6 * 128;
  for (int idx = blockIdx.x * blockDim.x + threadIdx.x; idx < total;
       idx += gridDim.x * blockDim.x) {
    if (idx < 131072) {
      int n = idx & 1023, c = idx >> 10;
      float v = (n < 512) ? load_in(desc1, n * 128 + c, bf)
                          : load_in(desc2, (n - 512) * 128 + c, bf);
      xt[((c >> 2) * 1024 + n) * 4 + (c & 3)] = v;
    } else if (idx < 147456) {
      int i = idx - 131072, hd = i >> 7, k = i & 127;
      W1t[i] = load_in(W1, k * 128 + hd, bf);
    } else if (idx < 163840) {
      W2f[idx - 147456] = load_in(W2, idx - 147456, bf);
    } else {
      int i = idx - 163840, o = i & 127;
      float v;
      if      (i < 128) v = load_in(as1, o, bf);
      else if (i < 256) v = load_in(ad1, o, bf);
      else if (i < 384) v = load_in(b1, o, bf);
      else if (i < 512) v = load_in(as2, o, bf);
      else if (i < 640) v = load_in(ad2, o, bf);
      else              v = load_in(b2, o, bf);
      vecs[i] = v;
    }
  }
}

// ------------------------------------------------------------ layer GEMM ----
// Ht[hd*1024 + node] = dot(x[node,:], W1[:,hd]).  512 blocks x 256 threads:
// block = (chunk of 256 nodes, head).  W column broadcast from LDS; x reads
// coalesced float4; write coalesced.  FMA order identical to R13 phase A.
__global__ __launch_bounds__(256, 2) void gemm_kernel(
    const float* __restrict__ xt_in, const float* __restrict__ W1t,
    float* __restrict__ Ht) {
  __shared__ float wcol[128];
  const int tid = threadIdx.x;
  const int hd = blockIdx.x & 127;
  const int chunk = blockIdx.x >> 7;
  const int node = chunk * 256 + tid;
  if (tid < 32) ((float4*)wcol)[tid] = ((const float4*)(W1t + hd * 128))[tid];
  __syncthreads();
  const float4* x4 = (const float4*)xt_in;
  float acc0 = 0.f, acc1 = 0.f;
  for (int cc = 0; cc < 32; cc += 8) {
    float4 xs[8];
#pragma unroll
    for (int u = 0; u < 8; ++u) xs[u] = x4[(cc + u) * 1024 + node];
#pragma unroll
    for (int u = 0; u < 8; ++u) {
      const int k = (cc + u) * 4;
      acc0 = fmaf(xs[u].x, wcol[k],     acc0);
      acc1 = fmaf(xs[u].y, wcol[k + 1], acc1);
      acc0 = fmaf(xs[u].z, wcol[k + 2], acc0);
      acc1 = fmaf(xs[u].w, wcol[k + 3], acc1);
    }
  }
  Ht[hd * 1024 + node] = acc0 + acc1;
}

// ------------------------------------------------------------ layer attn ----
// grid 256 = (S<<7)|hd, 512 threads.  Thread tid owns src node S*512+tid AND
// dst node D*512+tid.  h values read from Ht (2 coalesced loads); everything
// else verbatim R13.
template <int CROSS>
__global__ __launch_bounds__(512, 2) void attn_kernel(
    const float* __restrict__ Ht, float* __restrict__ xt_out,
    const float* __restrict__ vecs) {
  __shared__ float    sS[512];       // bucket-ordered s
  __shared__ float    sH[512];       // bucket-ordered h
  __shared__ unsigned hA[512];       // histogram
  __shared__ unsigned ISb[512];      // inclusive scan of hist
  __shared__ unsigned binNext[512];
  __shared__ float2   PRE[512];      // incl. prefix of (e2, e2*h), sorted ord
  __shared__ float2   SUF[512];      // incl. suffix of (e1, e1*h), sorted ord
  __shared__ float    red[16];
  __shared__ unsigned wTot[8];
  __shared__ float2   preTot[8];
  __shared__ float2   sufTot[8];

  const int tid  = threadIdx.x;
  const int lane = tid & 63;
  const int wave = tid >> 6;
  const int hd   = blockIdx.x & 127;
  const int S    = blockIdx.x >> 7;
  const int D    = CROSS ? (1 - S) : S;
  const float a_src = vecs[hd], a_dst = vecs[128 + hd], bias = vecs[256 + hd];

  const float h_src = Ht[hd * 1024 + S * 512 + tid];
  const float h_dst = CROSS ? Ht[hd * 1024 + D * 512 + tid] : h_src;
  const float s_own = h_src * a_src;
  const float d_own = h_dst * a_dst;

  // B1: block min/max of s (wave shuffle + LDS combine); zero hist.
  {
    float mnw = s_own, mxw = s_own;
#pragma unroll
    for (int off = 32; off > 0; off >>= 1) {
      mnw = fminf(mnw, __shfl_down(mnw, off));
      mxw = fmaxf(mxw, __shfl_down(mxw, off));
    }
    if (lane == 0) { red[wave] = mnw; red[8 + wave] = mxw; }
  }
  hA[tid] = 0;
  binNext[tid] = 0;
  __syncthreads();                                        // (1)
  const float mn = fminf(fminf(fminf(red[0], red[1]), fminf(red[2], red[3])),
                         fminf(fminf(red[4], red[5]), fminf(red[6], red[7])));
  const float mx = fmaxf(fmaxf(fmaxf(red[8], red[9]), fmaxf(red[10], red[11])),
                         fmaxf(fmaxf(red[12], red[13]), fmaxf(red[14], red[15])));
  const float scale = 512.0f / fmaxf(mx - mn, 1e-20f);

  // B2: histogram (bin(x) monotone non-decreasing).
  const int myBin = (int)fminf(fmaxf((s_own - mn) * scale, 0.0f), 511.0f);
  atomicAdd(&hA[myBin], 1u);
  __syncthreads();                                        // (2)

  // B3: inclusive scan of hist via wave shuffles + wave-total exchange.
  {
    unsigned v = hA[tid];
#pragma unroll
    for (int off = 1; off < 64; off <<= 1) {
      unsigned u = __shfl_up(v, off);
      if (lane >= off) v += u;
    }
    if (lane == 63) wTot[wave] = v;
    __syncthreads();                                      // (3)
    unsigned pre = 0;
#pragma unroll
    for (int w = 0; w < 8; ++w) pre += (w < wave) ? wTot[w] : 0u;
    ISb[tid] = v + pre;
    __syncthreads();                                      // (4)
  }

  // B4: scatter into bucket-ordered arrays (order within bucket free).
  {
    unsigned base = myBin ? ISb[myBin - 1] : 0u;
    unsigned pos = base + atomicAdd(&binNext[myBin], 1u);
    sS[pos] = s_own;
    sH[pos] = h_src;
  }
  __syncthreads();                                        // (5)

  // B5: exps + prefix(e2,e2h) / suffix(e1,e1h) via wave shuffles.
  {
    const float sv = sS[tid];
    const float hv = sH[tid];
    const float e1 = __expf(sv), e2 = __expf(0.2f * sv);
    float p0 = e2, p1 = e2 * hv;     // prefix pair
    float q0 = e1, q1 = e1 * hv;     // suffix pair
#pragma unroll
    for (int off = 1; off < 64; off <<= 1) {
      float u0 = __shfl_up(p0, off), u1 = __shfl_up(p1, off);
      if (lane >= off) { p0 += u0; p1 += u1; }
      float v0 = __shfl_down(q0, off), v1 = __shfl_down(q1, off);
      if (lane + off < 64) { q0 += v0; q1 += v1; }
    }
    if (lane == 63) preTot[wave] = make_float2(p0, p1);
    if (lane == 0)  sufTot[wave] = make_float2(q0, q1);
    __syncthreads();                                      // (6)
    float a0 = 0.f, a1 = 0.f, b0 = 0.f, b1 = 0.f;
#pragma unroll
    for (int w = 0; w < 8; ++w) {
      float2 pt = preTot[w], st = sufTot[w];
      if (w < wave) { a0 += pt.x; a1 += pt.y; }
      if (w > wave) { b0 += st.x; b1 += st.y; }
    }
    PRE[tid] = make_float2(p0 + a0, p1 + a1);
    SUF[tid] = make_float2(q0 + b0, q1 + b1);
    __syncthreads();                                      // (7)
  }

  // B7: per destination: bucket lookup + boundary-exact combine.
  {
    const float theta = -d_own;
    int b = (int)fminf(fmaxf((theta - mn) * scale, 0.0f), 511.0f);
    unsigned k0 = b ? ISb[b - 1] : 0u;  // elems in buckets < b: s < theta
    unsigned k1 = ISb[b];               // elems in buckets <= b
    float F1 = __expf(d_own), F2 = __expf(0.2f * d_own);
    float P2 = 0.f, P2h = 0.f, S1 = 0.f, S1h = 0.f;
    if (k0 > 0)   { float2 t2 = PRE[k0 - 1]; P2 = t2.x; P2h = t2.y; }
    if (k1 < 512) { float2 t2 = SUF[k1];     S1 = t2.x; S1h = t2.y; }
    float den = F1 * S1 + F2 * P2;
    float num = F1 * S1h + F2 * P2h;
    for (unsigned e = k0; e < k1; ++e) {  // boundary bucket: exact compare
      float se = sS[e], he = sH[e];
      float p = (se >= theta) ? F1 * __expf(se) : F2 * __expf(0.2f * se);
      den += p;
      num = fmaf(p, he, num);
    }
    if (CROSS) {  // self-loop: dst node's own source score
      float t = h_dst * a_src + d_own;
      float p = __expf(fmaxf(t, 0.2f * t));
      den += p;
      num = fmaf(p, h_dst, num);
    }
    float o = num / (den + 1e-16f) + bias;
    o = (o > 0.f) ? o : expm1f(o);  // ELU
    // packed layout: xt_out[((hd>>2)*1024 + node)*4 + (hd&3)]
    xt_out[(((hd >> 2) * 1024) + D * 512 + tid) * 4 + (hd & 3)] = o;
  }
}

// ----------------------------------------------------- final layer: mm2 ----
// grid 512 x 256: 2 rows x 128 cols per block.  h2 = x@W2, s2/d2 row dots.
__global__ __launch_bounds__(256, 2) void mm2_kernel(
    const float* __restrict__ xt_in, const float* __restrict__ W2f,
    const float* __restrict__ vecs, float* __restrict__ h2,
    float* __restrict__ s2, float* __restrict__ d2) {
  __shared__ float rs[256], rd[256];
  const int tid = threadIdx.x;
  const int row = blockIdx.x * 2 + (tid >> 7);
  const int c = tid & 127;
  float acc0 = 0.f, acc1 = 0.f;
  {
    const float4* x4 = (const float4*)xt_in;
    for (int cc = 0; cc < 32; cc += 8) {
      float4 xb[8];
#pragma unroll
      for (int u = 0; u < 8; ++u) xb[u] = x4[(cc + u) * 1024 + row];
#pragma unroll
      for (int u = 0; u < 8; ++u) {
        const int k = (cc + u) * 4;
        acc0 = fmaf(xb[u].x, W2f[k * 128 + c],       acc0);
        acc1 = fmaf(xb[u].y, W2f[(k + 1) * 128 + c], acc1);
        acc0 = fmaf(xb[u].z, W2f[(k + 2) * 128 + c], acc0);
        acc1 = fmaf(xb[u].w, W2f[(k + 3) * 128 + c], acc1);
      }
    }
  }
  float acc = acc0 + acc1;
  h2[row * 128 + c] = acc;
  rs[tid] = acc * vecs[384 + c];  // a_src2
  rd[tid] = acc * vecs[512 + c];  // a_dst2
  __syncthreads();
  for (int off = 64; off > 0; off >>= 1) {
    if ((tid & 127) < off) { rs[tid] += rs[tid + off]; rd[tid] += rd[tid + off]; }
    __syncthreads();
  }
  if ((tid & 127) == 0) {
    s2[row] = rs[tid];
    d2[row] = rd[tid];
  }
}

// ---------------------------------------------------- final layer: attn ----
// Final conv: heads=1, ch=128, cross edges + self, no ELU, +b2.
// 512 blocks x 256 threads: 2 dsts/block (2 blocks/CU vs R13's 1).
__global__ __launch_bounds__(256, 2) void att2_kernel(
    const float* __restrict__ h2, const float* __restrict__ s2,
    const float* __restrict__ d2, const float* __restrict__ vecs,
    void* __restrict__ out, const int* __restrict__ flag) {
  __shared__ __align__(16) float pT[512 * 2];  // pT[j*2 + ld]
  const int tid = threadIdx.x;
  const int dstBase = blockIdx.x * 2;
  const int srcBase = (dstBase < 512) ? 512 : 0;  // cross edges

  for (int e = tid; e < 1024; e += 256) {
    int j = e >> 1, ld = e & 1;
    float t = s2[srcBase + j] + d2[dstBase + ld];
    pT[e] = __expf(fmaxf(t, 0.2f * t));
  }
  __syncthreads();

  const int c = tid & 127;
  const int g = tid >> 7;            // 0 or 1 -> dst within block
  const int i0 = dstBase + g;
  float den = 0.f, num = 0.f;
  const float* hrow = h2 + srcBase * 128 + c;
  for (int j0 = 0; j0 < 512; j0 += 8) {
    float hb[8];
#pragma unroll
    for (int u = 0; u < 8; ++u) hb[u] = hrow[(j0 + u) * 128];
#pragma unroll
    for (int u = 0; u < 8; ++u) {
      float p = pT[(j0 + u) * 2 + g];
      den += p;
      num = fmaf(p, hb[u], num);
    }
  }
  // self-loop
  float ts = s2[i0] + d2[i0];
  float ps = __expf(fmaxf(ts, 0.2f * ts));
  den += ps;
  num = fmaf(ps, h2[i0 * 128 + c], num);

  float o = num / (den + 1e-16f) + vecs[640 + c];
  if (*flag) ((bf16*)out)[i0 * 128 + c] = __float2bfloat16(o);
  else       ((float*)out)[i0 * 128 + c] = o;
}

// ------------------------------------------------------------- launcher ----
extern "C" void kernel_launch(void* const* d_in, const int* in_sizes, int n_in,
                              void* d_out, int out_size, void* d_ws, size_t ws_size,
                              hipStream_t stream) {
  (void)in_sizes; (void)n_in; (void)out_size; (void)ws_size;
  float* ws   = (float*)d_ws;
  float* xtA  = ws;            // 131072 (packed float4 layout)
  float* xtB  = ws + 131072;   // 131072 (packed float4 layout)
  float* h2   = ws + 262144;   // 131072 (row-major); ALSO aliased as Ht
  float* Ht   = h2;            // Ht[hd*1024+node]; dead once mm2 runs
  float* W1t  = ws + 393216;   // 16384 (transposed W1)
  float* W2f  = ws + 409600;   // 16384
  float* vecs = ws + 425984;   // 768
  float* s2   = ws + 426752;   // 1024
  float* d2   = ws + 427776;   // 1024
  int*   flag = (int*)(ws + 428800);

  prep_kernel<<<128, 256, 0, stream>>>(d_in[0], d_in[1], d_in[2], d_in[3],
                                       d_in[4], d_in[5], d_in[6], d_in[7],
                                       d_in[8], d_in[9], xtA, W1t, W2f, vecs,
                                       flag);
  // L1 inside
  gemm_kernel<<<512, 256, 0, stream>>>(xtA, W1t, Ht);
  attn_kernel<0><<<256, 512, 0, stream>>>(Ht, xtB, vecs);
  // L2 cross
  gemm_kernel<<<512, 256, 0, stream>>>(xtB, W1t, Ht);
  attn_kernel<1><<<256, 512, 0, stream>>>(Ht, xtA, vecs);
  // L3 inside
  gemm_kernel<<<512, 256, 0, stream>>>(xtA, W1t, Ht);
  attn_kernel<0><<<256, 512, 0, stream>>>(Ht, xtB, vecs);
  // L4 cross
  gemm_kernel<<<512, 256, 0, stream>>>(xtB, W1t, Ht);
  attn_kernel<1><<<256, 512, 0, stream>>>(Ht, xtA, vecs);
  // final layer
  mm2_kernel<<<512, 256, 0, stream>>>(xtA, W2f, vecs, h2, s2, d2);
  att2_kernel<<<512, 256, 0, stream>>>(h2, s2, d2, vecs, d_out, flag);
}